// Round 5
// baseline (371.684 us; speedup 1.0000x reference)
//
#include <hip/hip_runtime.h>
#include <math.h>

// attention_block: B=8, C_IN=4, C_OUT=64, H=8, W=2048, d=C_OUT*H=512
// out = [x_out (8*512*2048) fp32] ++ [masked pre-softmax scores (8*2048*2048) fp32]
//
// R10: (1) scores_mfma gets the R8-proven dbuf stage-ahead pipeline (stage
// next K-chunk into the other LDS buffer BEFORE compute, 1 barrier/iter) --
// kills the per-iteration stage->drain latency exposure (MfmaUtil was 20.6%,
// nothing saturated). (2) combine_stats folded into out_bal's prologue
// (bit-identical op order on identical inputs). (3) proj_qk+proj_v fused into
// one launch. Numerics unchanged (split-bf16 3-MFMA, same masks).
//
// ws (~103 MB): Qhi,Qlo,Khi,Klo [b][w][d] bf16; Vhi,Vlo [b][d][w] bf16;
// stats [b][W][16] float2 (per-l-tile m, sum exp(v-m)).

#define B_ 8
#define W_ 2048
#define D_ 512
#define SCALE_ 0.04419417382415922f  // 1/sqrt(512)
#define NEG_BIG_ (-3.0e38f)

typedef __attribute__((ext_vector_type(8))) short bf16x8;
typedef __attribute__((ext_vector_type(4))) float f32x4;

__device__ __forceinline__ unsigned short f2bf(float x) {  // RNE truncate f32->bf16
  unsigned int u = __float_as_uint(x);
  u += 0x7fffu + ((u >> 16) & 1u);
  return (unsigned short)(u >> 16);
}
__device__ __forceinline__ float bf2f(unsigned short h) {
  return __uint_as_float(((unsigned int)h) << 16);
}
__device__ __forceinline__ void split2(float x, unsigned short& hi, unsigned short& lo) {
  hi = f2bf(x);
  lo = f2bf(x - bf2f(hi));
}

// async global->LDS, 16B per lane (dest = wave-uniform base + lane*16 pattern).
__device__ __forceinline__ void gl16(const unsigned short* g, unsigned short* l) {
  __builtin_amdgcn_global_load_lds(
      (__attribute__((address_space(1))) void*)const_cast<unsigned short*>(g),
      (__attribute__((address_space(3))) void*)l, 16, 0, 0);
}

// swizzled fragment address in a [R][32]-short tile: row*64B + (lq^f(row))*16B.
// f(row)=(row>>1)&3: conflict-free b128 column reads (verified R6: conflicts=0).
__device__ __forceinline__ int swz(int row, int lq) {
  return row * 32 + ((lq ^ ((row >> 1) & 3)) << 3);
}

// ---- fused projections: blocks [0,4096) -> Q,K [b][w][d]; [4096,8192) -> V [b][d][w] ----
__global__ __launch_bounds__(256) void proj_all(
    const float* __restrict__ x,
    const float* __restrict__ Wq, const float* __restrict__ bq,
    const float* __restrict__ Wk, const float* __restrict__ bk,
    const float* __restrict__ Wv, const float* __restrict__ bv,
    unsigned short* __restrict__ Qhi, unsigned short* __restrict__ Qlo,
    unsigned short* __restrict__ Khi, unsigned short* __restrict__ Klo,
    unsigned short* __restrict__ Vhi, unsigned short* __restrict__ Vlo) {
  int bid = blockIdx.x;
  if (bid < 4096) {
    // q,k path: thread = (b,w,o), 8 d-values, d-fastest output
    int idx = bid * 256 + threadIdx.x;   // B*W*64
    int o = idx & 63;
    int w = (idx >> 6) & (W_ - 1);
    int b = idx >> 17;
    const float* xb = x + (size_t)b * 32 * W_ + w;
    float xv[4][8];
#pragma unroll
    for (int c = 0; c < 4; c++)
#pragma unroll
      for (int h = 0; h < 8; h++) xv[c][h] = xb[(c * 8 + h) * W_];
    float wq0 = Wq[o * 4], wq1 = Wq[o * 4 + 1], wq2 = Wq[o * 4 + 2], wq3 = Wq[o * 4 + 3];
    float wk0 = Wk[o * 4], wk1 = Wk[o * 4 + 1], wk2 = Wk[o * 4 + 2], wk3 = Wk[o * 4 + 3];
    float bqv = bq[o], bkv = bk[o];
    unsigned short qh8[8] __attribute__((aligned(16))), ql8[8] __attribute__((aligned(16)));
    unsigned short kh8[8] __attribute__((aligned(16))), kl8[8] __attribute__((aligned(16)));
#pragma unroll
    for (int h = 0; h < 8; h++) {
      float q = bqv + wq0 * xv[0][h] + wq1 * xv[1][h] + wq2 * xv[2][h] + wq3 * xv[3][h];
      float k = bkv + wk0 * xv[0][h] + wk1 * xv[1][h] + wk2 * xv[2][h] + wk3 * xv[3][h];
      split2(q, qh8[h], ql8[h]);
      split2(k, kh8[h], kl8[h]);
    }
    size_t base = ((size_t)b * W_ + w) * D_ + o * 8;
    *(uint4*)&Qhi[base] = *(uint4*)qh8;
    *(uint4*)&Qlo[base] = *(uint4*)ql8;
    *(uint4*)&Khi[base] = *(uint4*)kh8;
    *(uint4*)&Klo[base] = *(uint4*)kl8;
  } else {
    // v path: thread = (b,d,w-chunk of 8), w-fastest output
    int idx = (bid - 4096) * 256 + threadIdx.x;   // B*D*256
    int wc = idx & 255;
    int d = (idx >> 8) & (D_ - 1);
    int b = idx >> 17;
    int o = d >> 3, h = d & 7;
    const float* xp = x + ((size_t)(b * 4) * 8 + h) * W_ + wc * 8;
    float4 xa[4][2];
#pragma unroll
    for (int c = 0; c < 4; c++) {
      xa[c][0] = *(const float4*)&xp[(size_t)c * 8 * W_];
      xa[c][1] = *(const float4*)&xp[(size_t)c * 8 * W_ + 4];
    }
    float w0 = Wv[o * 4], w1 = Wv[o * 4 + 1], w2 = Wv[o * 4 + 2], w3 = Wv[o * 4 + 3];
    float bvv = bv[o];
    unsigned short vh8[8] __attribute__((aligned(16))), vl8[8] __attribute__((aligned(16)));
#pragma unroll
    for (int j = 0; j < 8; j++) {
      float x0 = (j < 4) ? ((const float*)&xa[0][0])[j] : ((const float*)&xa[0][1])[j - 4];
      float x1 = (j < 4) ? ((const float*)&xa[1][0])[j] : ((const float*)&xa[1][1])[j - 4];
      float x2 = (j < 4) ? ((const float*)&xa[2][0])[j] : ((const float*)&xa[2][1])[j - 4];
      float x3 = (j < 4) ? ((const float*)&xa[3][0])[j] : ((const float*)&xa[3][1])[j - 4];
      float v = bvv + w0 * x0 + w1 * x1 + w2 * x2 + w3 * x3;
      split2(v, vh8[j], vl8[j]);
    }
    size_t base = ((size_t)b * D_ + d) * W_ + wc * 8;
    *(uint4*)&Vhi[base] = *(uint4*)vh8;
    *(uint4*)&Vlo[base] = *(uint4*)vl8;
  }
}

// ---- scores: S[k][l] = sum_d Q~[k][d]*K~[l][d] * SCALE, causal mask ----
// 128x128 block tile, 4 waves of 64x64, split-precision MFMA.
// Double-buffered stage-ahead pipeline: stage K-chunk i+1 into the other
// buffer BEFORE compute(i); ONE barrier per K-step (drains DMA issued a full
// body earlier). Epilogue emits per-row per-l-tile stats (m, sum exp(v-m)).
__global__ __launch_bounds__(256) void scores_mfma(
    const unsigned short* __restrict__ Qhi, const unsigned short* __restrict__ Qlo,
    const unsigned short* __restrict__ Khi, const unsigned short* __restrict__ Klo,
    float* __restrict__ S, float2* __restrict__ stats, const int* __restrict__ causal_p) {
  // flat dispatch id (x fastest); nwg = 2048, divisible by 8.
  int f = (blockIdx.z * 16 + blockIdx.y) * 16 + blockIdx.x;
  int lf = (f & 7) * 256 + (f >> 3);   // XCD j owns logical [j*256,(j+1)*256)
  int b = lf >> 8;
  int k0 = ((lf >> 4) & 15) * 128;
  int l0 = (lf & 15) * 128;
  int causal = *causal_p;
  int t = threadIdx.x;
  float* Sb = S + (size_t)b * W_ * W_;

  if (causal && (l0 + 127 < k0)) {   // tile fully below diagonal: fill, no stats
    float4 nb = make_float4(NEG_BIG_, NEG_BIG_, NEG_BIG_, NEG_BIG_);
    int row = t >> 1, c0 = (t & 1) * 64;
#pragma unroll
    for (int j = 0; j < 16; j++)
      *(float4*)&Sb[(size_t)(k0 + row) * W_ + l0 + c0 + j * 4] = nb;
    return;
  }

  __shared__ __align__(16) unsigned short qh_s[2][4096], ql_s[2][4096];
  __shared__ __align__(16) unsigned short kh_s[2][4096], kl_s[2][4096];   // 64 KB
  __shared__ float sm_h[2][128], ss_h[2][128];

  int wave = t >> 6, lane = t & 63;
  int wk0 = (wave >> 1) * 64, wl0 = (wave & 1) * 64;
  int lr = lane & 15, lq = lane >> 4;

  const unsigned short* Qhb = Qhi + ((size_t)b * W_ + k0) * D_;
  const unsigned short* Qlb = Qlo + ((size_t)b * W_ + k0) * D_;
  const unsigned short* Khb = Khi + ((size_t)b * W_ + l0) * D_;
  const unsigned short* Klb = Klo + ((size_t)b * W_ + l0) * D_;

  // staging: 512 slots = 128 rows x 4 chunks; thread owns slots t, t+256.
  // Global source chunk-permuted; LDS dest linear.
  int srow0 = t >> 2, sq = t & 3;
  int srow1 = srow0 + 64;
  size_t g0 = (size_t)srow0 * D_ + ((sq ^ ((srow0 >> 1) & 3)) << 3);
  size_t g1 = (size_t)srow1 * D_ + ((sq ^ ((srow1 >> 1) & 3)) << 3);
  int a0 = t * 8, a1 = t * 8 + 2048;   // shorts

  auto stage = [&](int buf, int d0) {
    gl16(Qhb + g0 + d0, &qh_s[buf][a0]);
    gl16(Qhb + g1 + d0, &qh_s[buf][a1]);
    gl16(Qlb + g0 + d0, &ql_s[buf][a0]);
    gl16(Qlb + g1 + d0, &ql_s[buf][a1]);
    gl16(Khb + g0 + d0, &kh_s[buf][a0]);
    gl16(Khb + g1 + d0, &kh_s[buf][a1]);
    gl16(Klb + g0 + d0, &kl_s[buf][a0]);
    gl16(Klb + g1 + d0, &kl_s[buf][a1]);
  };

  f32x4 acc[4][4];
#pragma unroll
  for (int i = 0; i < 4; i++)
#pragma unroll
    for (int j = 0; j < 4; j++) acc[i][j] = (f32x4){0.f, 0.f, 0.f, 0.f};

  // prologue: chunk 0 into buf 0
  stage(0, 0);
  __syncthreads();

  for (int i = 0; i < 16; i++) {
    int cur = i & 1;
    if (i < 15) stage(cur ^ 1, (i + 1) * 32);   // DMA lands during this body

    bf16x8 ah[4], al[4], bh[4], bl[4];
#pragma unroll
    for (int mt = 0; mt < 4; mt++) {
      int a = swz(wk0 + mt * 16 + lr, lq);
      ah[mt] = *(const bf16x8*)&qh_s[cur][a];
      al[mt] = *(const bf16x8*)&ql_s[cur][a];
    }
#pragma unroll
    for (int nt = 0; nt < 4; nt++) {
      int a = swz(wl0 + nt * 16 + lr, lq);
      bh[nt] = *(const bf16x8*)&kh_s[cur][a];
      bl[nt] = *(const bf16x8*)&kl_s[cur][a];
    }
    __builtin_amdgcn_s_setprio(1);
#pragma unroll
    for (int mt = 0; mt < 4; mt++)
#pragma unroll
      for (int nt = 0; nt < 4; nt++) {
        acc[mt][nt] = __builtin_amdgcn_mfma_f32_16x16x32_bf16(ah[mt], bh[nt], acc[mt][nt], 0, 0, 0);
        acc[mt][nt] = __builtin_amdgcn_mfma_f32_16x16x32_bf16(ah[mt], bl[nt], acc[mt][nt], 0, 0, 0);
        acc[mt][nt] = __builtin_amdgcn_mfma_f32_16x16x32_bf16(al[mt], bh[nt], acc[mt][nt], 0, 0, 0);
      }
    __builtin_amdgcn_s_setprio(0);
    __syncthreads();   // one barrier per K-step (drains DMA for buf cur^1)
  }

  // epilogue: store masked scores + per-row half-tile stats (64-col reduce).
  int wh = wl0 >> 6;
#pragma unroll
  for (int mt = 0; mt < 4; mt++)
#pragma unroll
    for (int r = 0; r < 4; r++) {
      int rr = wk0 + mt * 16 + lq * 4 + r;
      int k = k0 + rr;
      float v4[4];
#pragma unroll
      for (int nt = 0; nt < 4; nt++) {
        int l = l0 + wl0 + nt * 16 + lr;
        float s = acc[mt][nt][r] * SCALE_;
        if (causal && (l < k || s == 0.0f)) s = NEG_BIG_;  // faithful triu + zero->mask
        Sb[(size_t)k * W_ + l] = s;
        v4[nt] = s;
      }
      float mx = fmaxf(fmaxf(v4[0], v4[1]), fmaxf(v4[2], v4[3]));
#pragma unroll
      for (int off = 1; off < 16; off <<= 1) mx = fmaxf(mx, __shfl_xor(mx, off, 64));
      float ss = __expf(v4[0] - mx) + __expf(v4[1] - mx) +
                 __expf(v4[2] - mx) + __expf(v4[3] - mx);
#pragma unroll
      for (int off = 1; off < 16; off <<= 1) ss += __shfl_xor(ss, off, 64);
      if (lr == 0) { sm_h[wh][rr] = mx; ss_h[wh][rr] = ss; }
    }
  __syncthreads();
  if (t < 128) {
    float m0 = sm_h[0][t], m1 = sm_h[1][t];
    float s0 = ss_h[0][t], s1 = ss_h[1][t];
    float m = fmaxf(m0, m1);
    float ssum = s0 * __expf(m0 - m) + s1 * __expf(m1 - m);
    stats[((size_t)b * W_ + k0 + t) * 16 + (l0 >> 7)] = make_float2(m, ssum);
  }
}

// ---- out: O[d][k] = sum_l V[d][l] * P[k][l], P = exp(S-m)*inv (split bf16) ----
// Block = (b, k0 of 128, d-quarter of 128). 256 threads = 4 waves of 64d x 64k.
// Grid 512 = 2 blocks/CU; within-XCD dispatch order k0-ascending = LPT.
// Prologue combines per-tile stats -> m, inv locally (identical op order to
// the old combine_stats kernel; deterministic -> all dq blocks agree).
// Pipeline: S prefetch dist 2, writeP BEFORE MFMAs, V DMA dbuf, 1 barrier/chunk.
__global__ __launch_bounds__(256) void out_bal(
    const unsigned short* __restrict__ Vhi, const unsigned short* __restrict__ Vlo,
    const float* __restrict__ S, const float2* __restrict__ stats,
    float* __restrict__ O, const int* __restrict__ causal_p) {
  // flat id: grid (64,1,8) -> f = z*64 + x; nwg = 512, divisible by 8.
  int f = blockIdx.z * 64 + blockIdx.x;
  int lf = (f & 7) * 64 + (f >> 3);    // XCD j owns logical [j*64,(j+1)*64)
  int b = lf >> 6;
  int j2 = lf & 63;
  int k0 = (j2 >> 2) * 128;            // ascending within XCD -> LPT
  int dq = j2 & 3;                     // d-quarter: rows [dq*128, dq*128+128)
  int causal = *causal_p;
  int t = threadIdx.x;
  int wave = t >> 6, lane = t & 63;
  int wd0 = (wave >> 1) * 64;          // 0,64 within the 128-d quarter
  int wk0 = (wave & 1) * 64;           // 0,64 within the 128-k tile
  int lr = lane & 15, lq = lane >> 4;

  __shared__ __align__(16) unsigned short vh_s[2][128 * 32], vl_s[2][128 * 32];  // 32 KB
  __shared__ __align__(16) unsigned short ph_s[2][128 * 32], pl_s[2][128 * 32];  // 32 KB

  const unsigned short* Vhb = Vhi + ((size_t)b * D_ + dq * 128) * W_;
  const unsigned short* Vlb = Vlo + ((size_t)b * D_ + dq * 128) * W_;
  const float* Sb = S + (size_t)b * W_ * W_;

  // V staging: 512 slots = 128 rows x 4 chunks; thread owns slots t, t+256.
  int rA = t >> 2, qc = t & 3;
  int vx = (qc ^ ((rA >> 1) & 3)) << 3;
  const unsigned short* VhA = Vhb + (size_t)rA * W_ + vx;
  const unsigned short* VhB = VhA + (size_t)64 * W_;
  const unsigned short* VlA = Vlb + (size_t)rA * W_ + vx;
  const unsigned short* VlB = VlA + (size_t)64 * W_;
  int a0 = t * 8, a1 = t * 8 + 2048;   // linear LDS dest (shorts)

  // P staging: rows rA and rA+64, chunk qc; swizzled ds_write addrs.
  const float* SrowA = Sb + (size_t)(k0 + rA) * W_ + qc * 8;
  const float* SrowB = SrowA + (size_t)64 * W_;
  int pA = rA * 32 + vx;
  int pB = pA + 64 * 32;

  // inline stats combine (same op order as old combine_stats; lt0 is
  // wave-uniform since k>>7 == k0>>7 for all rows in this block).
  int lt0 = causal ? (k0 >> 7) : 0;
  const float2* spA = stats + ((size_t)b * W_ + k0 + rA) * 16;
  const float2* spB = spA + 64 * 16;
  float mA = -INFINITY, mB = -INFINITY;
  for (int lt = lt0; lt < 16; lt++) mA = fmaxf(mA, spA[lt].x);
  for (int lt = lt0; lt < 16; lt++) mB = fmaxf(mB, spB[lt].x);
  float sA = 0.f, sB = 0.f;
  for (int lt = lt0; lt < 16; lt++) sA += spA[lt].y * __expf(spA[lt].x - mA);
  for (int lt = lt0; lt < 16; lt++) sB += spB[lt].y * __expf(spB[lt].x - mB);
  float iA = 1.0f / sA, iB = 1.0f / sB;

  f32x4 acc[4][4];
#pragma unroll
  for (int i = 0; i < 4; i++)
#pragma unroll
    for (int j = 0; j < 4; j++) acc[i][j] = (f32x4){0.f, 0.f, 0.f, 0.f};

  int lstart = causal ? k0 : 0;        // P[k][l]=0 for l<k (S holds NEG_BIG there)
  int nch = (W_ - lstart) >> 5;        // multiple of 4

  auto stageV = [&](int buf, int l) {
    gl16(VhA + l, &vh_s[buf][a0]);
    gl16(VhB + l, &vh_s[buf][a1]);
    gl16(VlA + l, &vl_s[buf][a0]);
    gl16(VlB + l, &vl_s[buf][a1]);
  };
  auto writeP = [&](unsigned short* __restrict__ ph, unsigned short* __restrict__ pl,
                    float4 sa0, float4 sa1, float4 sb0, float4 sb1) {
    float p[8];
    unsigned short hi8[8] __attribute__((aligned(16)));
    unsigned short lo8[8] __attribute__((aligned(16)));
    p[0] = __expf(sa0.x - mA) * iA; p[1] = __expf(sa0.y - mA) * iA;
    p[2] = __expf(sa0.z - mA) * iA; p[3] = __expf(sa0.w - mA) * iA;
    p[4] = __expf(sa1.x - mA) * iA; p[5] = __expf(sa1.y - mA) * iA;
    p[6] = __expf(sa1.z - mA) * iA; p[7] = __expf(sa1.w - mA) * iA;
#pragma unroll
    for (int j = 0; j < 8; j++) split2(p[j], hi8[j], lo8[j]);
    *(uint4*)&ph[pA] = *(uint4*)hi8;
    *(uint4*)&pl[pA] = *(uint4*)lo8;
    p[0] = __expf(sb0.x - mB) * iB; p[1] = __expf(sb0.y - mB) * iB;
    p[2] = __expf(sb0.z - mB) * iB; p[3] = __expf(sb0.w - mB) * iB;
    p[4] = __expf(sb1.x - mB) * iB; p[5] = __expf(sb1.y - mB) * iB;
    p[6] = __expf(sb1.z - mB) * iB; p[7] = __expf(sb1.w - mB) * iB;
#pragma unroll
    for (int j = 0; j < 8; j++) split2(p[j], hi8[j], lo8[j]);
    *(uint4*)&ph[pB] = *(uint4*)hi8;
    *(uint4*)&pl[pB] = *(uint4*)lo8;
  };
  auto compute = [&](const unsigned short* vh, const unsigned short* vl,
                     const unsigned short* ph, const unsigned short* pl) {
    bf16x8 ah[4], al[4], bh[4], bl[4];
#pragma unroll
    for (int mt = 0; mt < 4; mt++) {
      int a = swz(wd0 + mt * 16 + lr, lq);
      ah[mt] = *(const bf16x8*)&vh[a];
      al[mt] = *(const bf16x8*)&vl[a];
    }
#pragma unroll
    for (int nt = 0; nt < 4; nt++) {
      int a = swz(wk0 + nt * 16 + lr, lq);
      bh[nt] = *(const bf16x8*)&ph[a];
      bl[nt] = *(const bf16x8*)&pl[a];
    }
    __builtin_amdgcn_s_setprio(1);
#pragma unroll
    for (int mt = 0; mt < 4; mt++)
#pragma unroll
      for (int nt = 0; nt < 4; nt++) {
        acc[mt][nt] = __builtin_amdgcn_mfma_f32_16x16x32_bf16(ah[mt], bh[nt], acc[mt][nt], 0, 0, 0);
        acc[mt][nt] = __builtin_amdgcn_mfma_f32_16x16x32_bf16(ah[mt], bl[nt], acc[mt][nt], 0, 0, 0);
        acc[mt][nt] = __builtin_amdgcn_mfma_f32_16x16x32_bf16(al[mt], bh[nt], acc[mt][nt], 0, 0, 0);
      }
    __builtin_amdgcn_s_setprio(0);
  };

  // S registers: even/odd chunk sets (named, no runtime indexing).
  float4 sAE0, sAE1, sBE0, sBE1, sAO0, sAO1, sBO0, sBO1;

  // prologue: S(0),S(1) in regs; V(0) DMA; P(0) written (waits S(0) once).
  sAE0 = *(const float4*)&SrowA[lstart];      sAE1 = *(const float4*)&SrowA[lstart + 4];
  sBE0 = *(const float4*)&SrowB[lstart];      sBE1 = *(const float4*)&SrowB[lstart + 4];
  sAO0 = *(const float4*)&SrowA[lstart + 32]; sAO1 = *(const float4*)&SrowA[lstart + 36];
  sBO0 = *(const float4*)&SrowB[lstart + 32]; sBO1 = *(const float4*)&SrowB[lstart + 36];
  stageV(0, lstart);
  writeP(&ph_s[0][0], &pl_s[0][0], sAE0, sAE1, sBE0, sBE1);
  __syncthreads();

  for (int ci = 0; ci < nch; ci += 2) {
    int base = lstart + ci * 32;
    // ---- even chunk ci: consumes buf0 ----
    if (ci + 2 < nch) {                // S(ci+2) -> E set
      sAE0 = *(const float4*)&SrowA[base + 64]; sAE1 = *(const float4*)&SrowA[base + 68];
      sBE0 = *(const float4*)&SrowB[base + 64]; sBE1 = *(const float4*)&SrowB[base + 68];
    }
    stageV(1, base + 32);              // V(ci+1) DMA (lands during this chunk)
    writeP(&ph_s[1][0], &pl_s[1][0], sAO0, sAO1, sBO0, sBO1);  // P(ci+1)
    compute(&vh_s[0][0], &vl_s[0][0], &ph_s[0][0], &pl_s[0][0]);
    __syncthreads();
    // ---- odd chunk ci+1: consumes buf1 ----
    bool more = (ci + 2 < nch);
    if (ci + 3 < nch) {                // S(ci+3) -> O set
      sAO0 = *(const float4*)&SrowA[base + 96]; sAO1 = *(const float4*)&SrowA[base + 100];
      sBO0 = *(const float4*)&SrowB[base + 96]; sBO1 = *(const float4*)&SrowB[base + 100];
    }
    if (more) {
      stageV(0, base + 64);            // V(ci+2) DMA
      writeP(&ph_s[0][0], &pl_s[0][0], sAE0, sAE1, sBE0, sBE1); // P(ci+2)
    }
    compute(&vh_s[1][0], &vl_s[1][0], &ph_s[1][0], &pl_s[1][0]);
    __syncthreads();
  }

#pragma unroll
  for (int mt = 0; mt < 4; mt++)
#pragma unroll
    for (int nt = 0; nt < 4; nt++)
#pragma unroll
      for (int r = 0; r < 4; r++) {
        int d = dq * 128 + wd0 + mt * 16 + lq * 4 + r;
        int k = k0 + wk0 + nt * 16 + lr;
        O[((size_t)b * D_ + d) * W_ + k] = acc[mt][nt][r];
      }
}

extern "C" void kernel_launch(void* const* d_in, const int* in_sizes, int n_in,
                              void* d_out, int out_size, void* d_ws, size_t ws_size,
                              hipStream_t stream) {
  const float* x  = (const float*)d_in[0];
  const float* Wq = (const float*)d_in[1];
  const float* bq = (const float*)d_in[2];
  const float* Wk = (const float*)d_in[3];
  const float* bk = (const float*)d_in[4];
  const float* Wv = (const float*)d_in[5];
  const float* bv = (const float*)d_in[6];
  const int* causal = (const int*)d_in[7];

  float* out = (float*)d_out;
  float* x_out = out;                                   // 8*512*2048
  float* S = out + (size_t)B_ * D_ * W_;                // 8*2048*2048

  const size_t NQ = (size_t)B_ * W_ * D_;               // 8,388,608
  unsigned short* wsu = (unsigned short*)d_ws;
  unsigned short* Qhi = wsu;
  unsigned short* Qlo = wsu + NQ;
  unsigned short* Khi = wsu + 2 * NQ;
  unsigned short* Klo = wsu + 3 * NQ;
  unsigned short* Vhi = wsu + 4 * NQ;
  unsigned short* Vlo = wsu + 5 * NQ;
  float2* stats = (float2*)(wsu + 6 * NQ);              // B_*W_*16 float2 = 2 MB

  proj_all<<<8192, 256, 0, stream>>>(x, Wq, bq, Wk, bk, Wv, bv,
                                     Qhi, Qlo, Khi, Klo, Vhi, Vlo);
  scores_mfma<<<dim3(16, 16, B_), 256, 0, stream>>>(Qhi, Qlo, Khi, Klo, S, stats, causal);
  out_bal<<<dim3(64, 1, B_), 256, 0, stream>>>(Vhi, Vlo, S, stats, x_out, causal);
}